// Round 1
// baseline (259.438 us; speedup 1.0000x reference)
//
#include <hip/hip_runtime.h>
#include <hip/hip_bf16.h>
#include <math.h>

// Problem constants (B=2, S=2048, d0=512, d1=64, basis=64, G=8)
#define SEQ  2048
#define ROWS 4096          // B * S
#define D0   512
#define D1   64

// ---------------------------------------------------------------------------
// Generic tiled GEMM:  C[m,n] = sum_k A[m,k] * W[n,k]   (A: MxK, W: NxK, both
// row-major, K contiguous — "NT" layout). BM=BN=64, BK=16, 256 thr, 4x4 micro.
// M % 64 == 0, N % 64 == 0, K % 16 == 0 (true for all 5 call sites).
// ---------------------------------------------------------------------------
__global__ __launch_bounds__(256) void gemm_nt(const float* __restrict__ A,
                                               const float* __restrict__ W,
                                               float* __restrict__ C,
                                               int M, int N, int K) {
    __shared__ __align__(16) float a_sh[16][64];
    __shared__ __align__(16) float w_sh[16][64];
    const int tid = threadIdx.x;
    const int bm = blockIdx.y * 64;
    const int bn = blockIdx.x * 64;
    const int tx = tid & 15;   // -> n
    const int ty = tid >> 4;   // -> m
    const int lm = tid >> 2;         // staging row 0..63
    const int lk = (tid & 3) * 4;    // staging k offset 0,4,8,12

    float acc[4][4] = {};

    for (int kc = 0; kc < K; kc += 16) {
        float4 av = *(const float4*)(A + (bm + lm) * K + kc + lk);
        float4 wv = *(const float4*)(W + (bn + lm) * K + kc + lk);
        __syncthreads();  // previous iteration's LDS reads complete
        a_sh[lk + 0][lm] = av.x; a_sh[lk + 1][lm] = av.y;
        a_sh[lk + 2][lm] = av.z; a_sh[lk + 3][lm] = av.w;
        w_sh[lk + 0][lm] = wv.x; w_sh[lk + 1][lm] = wv.y;
        w_sh[lk + 2][lm] = wv.z; w_sh[lk + 3][lm] = wv.w;
        __syncthreads();
#pragma unroll
        for (int k = 0; k < 16; ++k) {
            float4 a4 = *(const float4*)&a_sh[k][ty * 4];
            float4 w4 = *(const float4*)&w_sh[k][tx * 4];
            acc[0][0] = fmaf(a4.x, w4.x, acc[0][0]);
            acc[0][1] = fmaf(a4.x, w4.y, acc[0][1]);
            acc[0][2] = fmaf(a4.x, w4.z, acc[0][2]);
            acc[0][3] = fmaf(a4.x, w4.w, acc[0][3]);
            acc[1][0] = fmaf(a4.y, w4.x, acc[1][0]);
            acc[1][1] = fmaf(a4.y, w4.y, acc[1][1]);
            acc[1][2] = fmaf(a4.y, w4.z, acc[1][2]);
            acc[1][3] = fmaf(a4.y, w4.w, acc[1][3]);
            acc[2][0] = fmaf(a4.z, w4.x, acc[2][0]);
            acc[2][1] = fmaf(a4.z, w4.y, acc[2][1]);
            acc[2][2] = fmaf(a4.z, w4.z, acc[2][2]);
            acc[2][3] = fmaf(a4.z, w4.w, acc[2][3]);
            acc[3][0] = fmaf(a4.w, w4.x, acc[3][0]);
            acc[3][1] = fmaf(a4.w, w4.y, acc[3][1]);
            acc[3][2] = fmaf(a4.w, w4.z, acc[3][2]);
            acc[3][3] = fmaf(a4.w, w4.w, acc[3][3]);
        }
    }
#pragma unroll
    for (int i = 0; i < 4; ++i) {
        float4 o;
        o.x = acc[i][0]; o.y = acc[i][1]; o.z = acc[i][2]; o.w = acc[i][3];
        *(float4*)(C + (bm + ty * 4 + i) * N + bn + tx * 4) = o;
    }
}

// ---------------------------------------------------------------------------
// Block-wide (256 thr = 4 waves) sum of two floats.
// ---------------------------------------------------------------------------
__device__ inline void block_reduce_2(float& a, float& b, float* sh) {
    const int tid = threadIdx.x;
#pragma unroll
    for (int o = 32; o; o >>= 1) {
        a += __shfl_down(a, o, 64);
        b += __shfl_down(b, o, 64);
    }
    if ((tid & 63) == 0) { sh[tid >> 6] = a; sh[(tid >> 6) + 4] = b; }
    __syncthreads();
    a = sh[0] + sh[1] + sh[2] + sh[3];
    b = sh[4] + sh[5] + sh[6] + sh[7];
    __syncthreads();
}

// ---------------------------------------------------------------------------
// RN epilogue (layers 1 & 3): one block per row r (512 wide).
//   n = LN(Y[r], g, be);  scal = dot(n, Bb[r%64, :]);
//   OUT[r] = scal * Aa[:, r%64] + RES[r]
// ---------------------------------------------------------------------------
__global__ __launch_bounds__(256) void ln_rn_kernel(
        const float* __restrict__ Y, const float* __restrict__ RES,
        const float* __restrict__ g, const float* __restrict__ be,
        const float* __restrict__ Bb,   // 64 x 512
        const float* __restrict__ Aa,   // 512 x 64
        float* __restrict__ OUT) {
    __shared__ float sh[8];
    const int r = blockIdx.x;
    const int tid = threadIdx.x;
    const float* y = Y + r * D0;
    float y0 = y[tid], y1 = y[tid + 256];
    float sum = y0 + y1;
    float ssq = y0 * y0 + y1 * y1;
    block_reduce_2(sum, ssq, sh);
    float mean = sum * (1.0f / 512.0f);
    float var  = ssq * (1.0f / 512.0f) - mean * mean;
    float rstd = rsqrtf(var + 1e-5f);
    float n0 = (y0 - mean) * rstd * g[tid]       + be[tid];
    float n1 = (y1 - mean) * rstd * g[tid + 256] + be[tid + 256];
    const int jm = r & 63;   // (r % 2048) % 64 == r % 64 since 64 | 2048
    float p = n0 * Bb[jm * D0 + tid] + n1 * Bb[jm * D0 + tid + 256];
    float zero = 0.f;
    block_reduce_2(p, zero, sh);
    OUT[r * D0 + tid]       = p * Aa[tid * 64 + jm]         + RES[r * D0 + tid];
    OUT[r * D0 + tid + 256] = p * Aa[(tid + 256) * 64 + jm] + RES[r * D0 + tid + 256];
}

// ---------------------------------------------------------------------------
// TS layer: one block per sequence position s.
//   t[b] = LN(Y2[b,s], g2, b2)                     (64-wide, wave reduce)
//   Wp[i,j] = sum_g P[i,j,g] * cos(2*pi*s / (i*512 + j*8 + g + 2))
//   H2[b,s,i] = sum_j Wp[i,j]*t[b,j] + Rr[b,s,i]
// cos: exact integer remainder rem = s - floor(s*rcp(p))*p, then v_cos_f32 on
// rem/p revolutions. Cosine evenness/periodicity absorbs rcp rounding.
// ---------------------------------------------------------------------------
__global__ __launch_bounds__(256) void ts_kernel(
        const float* __restrict__ Y2, const float* __restrict__ g2,
        const float* __restrict__ b2, const float* __restrict__ P,
        const float* __restrict__ Rr, float* __restrict__ H2) {
    __shared__ float tsh[2][64];
    __shared__ float part[4][2][64];
    const int s = blockIdx.x;
    const int tid = threadIdx.x;

    if (tid < 128) {             // waves 0,1 fully active
        int b = tid >> 6, j = tid & 63;
        float v = Y2[(b * SEQ + s) * D1 + j];
        float sum = v, ssq = v * v;
#pragma unroll
        for (int o = 32; o; o >>= 1) {
            sum += __shfl_down(sum, o, 64);
            ssq += __shfl_down(ssq, o, 64);
        }
        sum = __shfl(sum, 0, 64);
        ssq = __shfl(ssq, 0, 64);
        float mean = sum * (1.0f / 64.0f);
        float var  = ssq * (1.0f / 64.0f) - mean * mean;
        float rstd = rsqrtf(var + 1e-5f);
        tsh[b][j] = (v - mean) * rstd * g2[j] + b2[j];
    }
    __syncthreads();

    const int i  = tid & 63;
    const int jg = tid >> 6;           // 4 j-groups of 16
    const float sf = (float)s;
    float a0 = 0.f, a1 = 0.f;
    for (int jj = 0; jj < 16; ++jj) {
        int j = (jg << 4) + jj;
        const float* pp = P + (i * 64 + j) * 8;
        float base = (float)(i * 512 + j * 8 + 2);
        float w = 0.f;
#pragma unroll
        for (int gg = 0; gg < 8; ++gg) {
            float pval = base + (float)gg;
            float invp = __builtin_amdgcn_rcpf(pval);
            float q    = floorf(sf * invp);
            float rem  = fmaf(-q, pval, sf);    // exact small integer
            float fr   = rem * invp;            // revolutions, in (-1, 2)
            fr = fr - floorf(fr);               // [0,1) for v_cos
            float c = __builtin_amdgcn_cosf(fr); // cos(2*pi*fr)
            w = fmaf(pp[gg], c, w);
        }
        a0 = fmaf(w, tsh[0][j], a0);
        a1 = fmaf(w, tsh[1][j], a1);
    }
    part[jg][0][i] = a0;
    part[jg][1][i] = a1;
    __syncthreads();

    if (tid < 128) {
        int b = tid >> 6, ii = tid & 63;
        float nk = part[0][b][ii] + part[1][b][ii] + part[2][b][ii] + part[3][b][ii];
        int idx = (b * SEQ + s) * D1 + ii;
        H2[idx] = nk + Rr[idx];
    }
}

// ---------------------------------------------------------------------------
extern "C" void kernel_launch(void* const* d_in, const int* in_sizes, int n_in,
                              void* d_out, int out_size, void* d_ws, size_t ws_size,
                              hipStream_t stream) {
    const float* x  = (const float*)d_in[0];
    const float* W1 = (const float*)d_in[1];
    const float* g1 = (const float*)d_in[2];
    const float* b1 = (const float*)d_in[3];
    const float* A1 = (const float*)d_in[4];
    const float* B1 = (const float*)d_in[5];
    const float* M2 = (const float*)d_in[6];
    const float* g2 = (const float*)d_in[7];
    const float* b2 = (const float*)d_in[8];
    const float* P2 = (const float*)d_in[9];
    const float* R2 = (const float*)d_in[10];
    const float* W3 = (const float*)d_in[11];
    const float* g3 = (const float*)d_in[12];
    const float* b3 = (const float*)d_in[13];
    const float* A3 = (const float*)d_in[14];
    const float* B3 = (const float*)d_in[15];
    const float* R3 = (const float*)d_in[16];

    float* ws = (float*)d_ws;
    float* y1 = ws;                    // 4096*512       (later reused as y3)
    float* h1 = ws + 2097152;          // 4096*512       (later reused as r3)
    float* y2 = ws + 4194304;          // 4096*64
    float* r2 = ws + 4456448;          // 4096*64
    float* h2 = ws + 4718592;          // 4096*64
    // total: 4,980,736 floats = ~19.9 MB of d_ws

    dim3 blk(256);

    // Layer 1: y1 = x @ W1^T ; h1 = RN-epilogue(y1, x)
    gemm_nt<<<dim3(8, 64), blk, 0, stream>>>(x, W1, y1, ROWS, D0, D0);
    ln_rn_kernel<<<ROWS, blk, 0, stream>>>(y1, x, g1, b1, B1, A1, h1);

    // Layer 2: y2 = h1 @ M2^T ; r2 = h1 @ R2^T ; h2 = TS(y2, P2) + r2
    gemm_nt<<<dim3(1, 64), blk, 0, stream>>>(h1, M2, y2, ROWS, D1, D0);
    gemm_nt<<<dim3(1, 64), blk, 0, stream>>>(h1, R2, r2, ROWS, D1, D0);
    ts_kernel<<<SEQ, blk, 0, stream>>>(y2, g2, b2, P2, r2, h2);

    // Layer 3: y3 = h2 @ W3^T ; r3 = h2 @ R3^T ; out = RN-epilogue(y3, r3)
    float* y3 = y1;   // y1 dead after first epilogue
    float* r3 = h1;   // h1 dead after layer-2 GEMMs
    gemm_nt<<<dim3(8, 64), blk, 0, stream>>>(h2, W3, y3, ROWS, D0, D1);
    gemm_nt<<<dim3(8, 64), blk, 0, stream>>>(h2, R3, r3, ROWS, D0, D1);
    ln_rn_kernel<<<ROWS, blk, 0, stream>>>(y3, r3, g3, b3, B3, A3, (float*)d_out);
}

// Round 2
// 189.255 us; speedup vs baseline: 1.3708x; 1.3708x over previous
//
#include <hip/hip_runtime.h>
#include <hip/hip_bf16.h>
#include <math.h>

#define SEQ  2048
#define ROWS 4096          // B * S
#define D0   512
#define D1   64

typedef short bf8 __attribute__((ext_vector_type(8)));   // 8 bf16 = 4 VGPRs
typedef float f4  __attribute__((ext_vector_type(4)));   // MFMA acc

// ---------------------------------------------------------------------------
// fp32 -> bf16 hi/lo split helpers (round-to-nearest-even)
// ---------------------------------------------------------------------------
__device__ __forceinline__ unsigned short f2bf(float f) {
    unsigned u = __float_as_uint(f);
    return (unsigned short)((u + 0x7fffu + ((u >> 16) & 1u)) >> 16);
}
__device__ __forceinline__ void hilo(float f, unsigned short& h, unsigned short& l) {
    h = f2bf(f);
    float fh = __uint_as_float((unsigned)h << 16);
    l = f2bf(f - fh);
}

// ---------------------------------------------------------------------------
// async global->LDS 16B copy
// ---------------------------------------------------------------------------
__device__ __forceinline__ void async16(const void* g, void* l) {
    __builtin_amdgcn_global_load_lds(
        (const __attribute__((address_space(1))) unsigned int*)g,
        (__attribute__((address_space(3))) unsigned int*)l, 16, 0, 0);
}

// ---------------------------------------------------------------------------
// Conversion kernel: fp32 sources -> bf16 hi/lo planes.
// Flat concat: Wc2 = [M2;R2] (128x512), Wc3 = [W3;R3] (1024x64).
// 1024 elements per block, 2432 blocks.
// ---------------------------------------------------------------------------
__global__ __launch_bounds__(256) void convk(
        const float* __restrict__ x,  const float* __restrict__ W1,
        const float* __restrict__ M2, const float* __restrict__ R2,
        const float* __restrict__ W3, const float* __restrict__ R3,
        unsigned short* __restrict__ xh,  unsigned short* __restrict__ xl,
        unsigned short* __restrict__ W1h, unsigned short* __restrict__ W1l,
        unsigned short* __restrict__ C2h, unsigned short* __restrict__ C2l,
        unsigned short* __restrict__ C3h, unsigned short* __restrict__ C3l) {
    int b = blockIdx.x;
    const float* src; unsigned short *dh, *dl; int off;
    if      (b < 2048) { src = x;  dh = xh;          dl = xl;          off = b; }
    else if (b < 2304) { src = W1; dh = W1h;         dl = W1l;         off = b - 2048; }
    else if (b < 2336) { src = M2; dh = C2h;         dl = C2l;         off = b - 2304; }
    else if (b < 2368) { src = R2; dh = C2h + 32768; dl = C2l + 32768; off = b - 2336; }
    else if (b < 2400) { src = W3; dh = C3h;         dl = C3l;         off = b - 2368; }
    else               { src = R3; dh = C3h + 32768; dl = C3l + 32768; off = b - 2400; }
    int idx = off * 1024 + threadIdx.x * 4;
    float4 v = *(const float4*)(src + idx);
    ushort4 hv, lv;
    hilo(v.x, hv.x, lv.x); hilo(v.y, hv.y, lv.y);
    hilo(v.z, hv.z, lv.z); hilo(v.w, hv.w, lv.w);
    *(ushort4*)(dh + idx) = hv;
    *(ushort4*)(dl + idx) = lv;
}

// ---------------------------------------------------------------------------
// bf16x3 MFMA GEMM:  C[m,n] = sum_k A[m,k]*W[n,k], A ~ Ah+Al, W ~ Wh+Wl.
// Tile 128(M) x 64(N), BK=64, 256 threads (4 waves, each owns 32 m-rows).
// grid: x = N/64, y = M/128, z = K-split (k0 = z*Ks, C += z*M*N).
// ---------------------------------------------------------------------------
__global__ __launch_bounds__(256) void gemm_bf3(
        const unsigned short* __restrict__ Ah, const unsigned short* __restrict__ Al,
        const unsigned short* __restrict__ Wh, const unsigned short* __restrict__ Wl,
        float* __restrict__ C, int M, int N, int K, int Ks) {
    __shared__ __align__(16) unsigned short aH[128 * 64], aL[128 * 64];
    __shared__ __align__(16) unsigned short wH[64 * 64],  wL[64 * 64];
    const int tid = threadIdx.x;
    const int wv  = tid >> 6;        // wave 0..3
    const int ln  = tid & 63;
    const int lm  = ln & 15;         // m/n within 16-tile
    const int lq  = ln >> 4;         // quad 0..3
    const int bm  = blockIdx.y * 128;
    const int bn  = blockIdx.x * 64;
    const int k0  = blockIdx.z * Ks;
    C += (size_t)blockIdx.z * M * N;

    f4 acc[2][4] = {};

    for (int kt = 0; kt < Ks; kt += 64) {
        const int kg = k0 + kt;
        __syncthreads();   // all waves done reading previous tile
        // stage A planes: wave wv covers rows [wv*32, wv*32+32), 8 chunks/row
#pragma unroll
        for (int i = 0; i < 4; ++i) {
            int c = i * 64 + ln;                 // 0..255
            int row = wv * 32 + (c >> 3);
            int ch  = c & 7;
            size_t go = (size_t)(bm + row) * K + kg + ch * 8;
            int    lo = row * 64 + ch * 8;
            async16(Ah + go, aH + lo);
            async16(Al + go, aL + lo);
        }
        // stage W planes: wave wv covers rows [wv*16, wv*16+16)
#pragma unroll
        for (int i = 0; i < 2; ++i) {
            int c = i * 64 + ln;                 // 0..127
            int row = wv * 16 + (c >> 3);
            int ch  = c & 7;
            size_t go = (size_t)(bn + row) * K + kg + ch * 8;
            int    lo = row * 64 + ch * 8;
            async16(Wh + go, wH + lo);
            async16(Wl + go, wL + lo);
        }
        __syncthreads();   // drains vmcnt (compiler emits waitcnt before barrier)

#pragma unroll
        for (int kk = 0; kk < 2; ++kk) {
            bf8 ah[2], al[2], bh[4], bl[4];
#pragma unroll
            for (int t = 0; t < 2; ++t) {
                int off = (wv * 32 + t * 16 + lm) * 64 + kk * 32 + lq * 8;
                ah[t] = *(const bf8*)(aH + off);
                al[t] = *(const bf8*)(aL + off);
            }
#pragma unroll
            for (int u = 0; u < 4; ++u) {
                int off = (u * 16 + lm) * 64 + kk * 32 + lq * 8;
                bh[u] = *(const bf8*)(wH + off);
                bl[u] = *(const bf8*)(wL + off);
            }
#pragma unroll
            for (int t = 0; t < 2; ++t)
#pragma unroll
                for (int u = 0; u < 4; ++u) {
                    acc[t][u] = __builtin_amdgcn_mfma_f32_16x16x32_bf16(ah[t], bh[u], acc[t][u], 0, 0, 0);
                    acc[t][u] = __builtin_amdgcn_mfma_f32_16x16x32_bf16(ah[t], bl[u], acc[t][u], 0, 0, 0);
                    acc[t][u] = __builtin_amdgcn_mfma_f32_16x16x32_bf16(al[t], bh[u], acc[t][u], 0, 0, 0);
                }
        }
    }

    // C/D layout: col = lane&15, row = quad*4 + reg
#pragma unroll
    for (int t = 0; t < 2; ++t)
#pragma unroll
        for (int u = 0; u < 4; ++u) {
            int row = bm + wv * 32 + t * 16 + lq * 4;
            int col = bn + u * 16 + lm;
#pragma unroll
            for (int r = 0; r < 4; ++r)
                C[(size_t)(row + r) * N + col] = acc[t][u][r];
        }
}

// ---------------------------------------------------------------------------
// Block-wide (256 thr) sum of two floats.
// ---------------------------------------------------------------------------
__device__ __forceinline__ void block_reduce_2(float& a, float& b, float* sh) {
    const int tid = threadIdx.x;
#pragma unroll
    for (int o = 32; o; o >>= 1) {
        a += __shfl_down(a, o, 64);
        b += __shfl_down(b, o, 64);
    }
    if ((tid & 63) == 0) { sh[tid >> 6] = a; sh[(tid >> 6) + 4] = b; }
    __syncthreads();
    a = sh[0] + sh[1] + sh[2] + sh[3];
    b = sh[4] + sh[5] + sh[6] + sh[7];
    __syncthreads();
}

// ---------------------------------------------------------------------------
// RN epilogue: LN(Y row) -> scal = dot(n, Bb[r%64]) -> scal*Aa[:,r%64] + RES.
// Output either fp32 (outf) or bf16 hi/lo planes (outh/outl).
// ---------------------------------------------------------------------------
__global__ __launch_bounds__(256) void ln_rn_kernel(
        const float* __restrict__ Y, int ldy,
        const float* __restrict__ RES, int ldr,
        const float* __restrict__ g, const float* __restrict__ be,
        const float* __restrict__ Bb,   // 64 x 512
        const float* __restrict__ Aa,   // 512 x 64
        float* __restrict__ outf,
        unsigned short* __restrict__ outh, unsigned short* __restrict__ outl) {
    __shared__ float sh[8];
    const int r = blockIdx.x;
    const int tid = threadIdx.x;
    const float* y = Y + (size_t)r * ldy;
    float y0 = y[tid], y1 = y[tid + 256];
    float sum = y0 + y1;
    float ssq = y0 * y0 + y1 * y1;
    block_reduce_2(sum, ssq, sh);
    float mean = sum * (1.0f / 512.0f);
    float var  = ssq * (1.0f / 512.0f) - mean * mean;
    float rstd = rsqrtf(var + 1e-5f);
    float n0 = (y0 - mean) * rstd * g[tid]       + be[tid];
    float n1 = (y1 - mean) * rstd * g[tid + 256] + be[tid + 256];
    const int jm = r & 63;
    float p = n0 * Bb[jm * D0 + tid] + n1 * Bb[jm * D0 + tid + 256];
    float zero = 0.f;
    block_reduce_2(p, zero, sh);
    const float* res = RES + (size_t)r * ldr;
    float v0 = p * Aa[tid * 64 + jm]         + res[tid];
    float v1 = p * Aa[(tid + 256) * 64 + jm] + res[tid + 256];
    if (outf) {
        outf[(size_t)r * D0 + tid]       = v0;
        outf[(size_t)r * D0 + tid + 256] = v1;
    }
    if (outh) {
        unsigned short h, l;
        hilo(v0, h, l);
        outh[(size_t)r * D0 + tid] = h;       outl[(size_t)r * D0 + tid] = l;
        hilo(v1, h, l);
        outh[(size_t)r * D0 + tid + 256] = h; outl[(size_t)r * D0 + tid + 256] = l;
    }
}

// ---------------------------------------------------------------------------
// TS layer. C2 = two split-K partial buffers, each (4096 x 128):
// cols [0,64) = y2 (M2 path), cols [64,128) = r2 (R2 residual path).
// Output: bf16 hi/lo planes of h2 (4096 x 64).
// ---------------------------------------------------------------------------
#define C2_SPLIT (ROWS * 128)
__global__ __launch_bounds__(256) void ts_kernel(
        const float* __restrict__ C2, const float* __restrict__ g2,
        const float* __restrict__ b2, const float* __restrict__ P,
        unsigned short* __restrict__ Hh, unsigned short* __restrict__ Hl) {
    __shared__ float tsh[2][64];
    __shared__ float rsh[2][64];
    __shared__ float part[4][2][64];
    const int s = blockIdx.x;
    const int tid = threadIdx.x;

    if (tid < 128) {
        int b = tid >> 6, j = tid & 63;
        int bs = b * SEQ + s;
        float v  = C2[(size_t)bs * 128 + j]      + C2[C2_SPLIT + (size_t)bs * 128 + j];
        float rv = C2[(size_t)bs * 128 + 64 + j] + C2[C2_SPLIT + (size_t)bs * 128 + 64 + j];
        rsh[b][j] = rv;
        float sum = v, ssq = v * v;
#pragma unroll
        for (int o = 32; o; o >>= 1) {
            sum += __shfl_down(sum, o, 64);
            ssq += __shfl_down(ssq, o, 64);
        }
        sum = __shfl(sum, 0, 64);
        ssq = __shfl(ssq, 0, 64);
        float mean = sum * (1.0f / 64.0f);
        float var  = ssq * (1.0f / 64.0f) - mean * mean;
        float rstd = rsqrtf(var + 1e-5f);
        tsh[b][j] = (v - mean) * rstd * g2[j] + b2[j];
    }
    __syncthreads();

    const int i  = tid & 63;
    const int jg = tid >> 6;
    const float sf = (float)s;
    float a0 = 0.f, a1 = 0.f;
    for (int jj = 0; jj < 16; ++jj) {
        int j = (jg << 4) + jj;
        const float* pp = P + (i * 64 + j) * 8;
        float base = (float)(i * 512 + j * 8 + 2);
        float w = 0.f;
#pragma unroll
        for (int gg = 0; gg < 8; ++gg) {
            float pval = base + (float)gg;
            float invp = __builtin_amdgcn_rcpf(pval);
            float q    = floorf(sf * invp);
            float rem  = fmaf(-q, pval, sf);
            float fr   = rem * invp;
            fr = fr - floorf(fr);
            float c = __builtin_amdgcn_cosf(fr);
            w = fmaf(pp[gg], c, w);
        }
        a0 = fmaf(w, tsh[0][j], a0);
        a1 = fmaf(w, tsh[1][j], a1);
    }
    part[jg][0][i] = a0;
    part[jg][1][i] = a1;
    __syncthreads();

    if (tid < 128) {
        int b = tid >> 6, ii = tid & 63;
        float nk = part[0][b][ii] + part[1][b][ii] + part[2][b][ii] + part[3][b][ii]
                 + rsh[b][ii];
        size_t idx = (size_t)(b * SEQ + s) * D1 + ii;
        unsigned short h, l;
        hilo(nk, h, l);
        Hh[idx] = h; Hl[idx] = l;
    }
}

// ---------------------------------------------------------------------------
extern "C" void kernel_launch(void* const* d_in, const int* in_sizes, int n_in,
                              void* d_out, int out_size, void* d_ws, size_t ws_size,
                              hipStream_t stream) {
    const float* x  = (const float*)d_in[0];
    const float* W1 = (const float*)d_in[1];
    const float* g1 = (const float*)d_in[2];
    const float* b1 = (const float*)d_in[3];
    const float* A1 = (const float*)d_in[4];
    const float* B1 = (const float*)d_in[5];
    const float* M2 = (const float*)d_in[6];
    const float* g2 = (const float*)d_in[7];
    const float* b2 = (const float*)d_in[8];
    const float* P2 = (const float*)d_in[9];
    const float* R2 = (const float*)d_in[10];
    const float* W3 = (const float*)d_in[11];
    const float* g3 = (const float*)d_in[12];
    const float* b3 = (const float*)d_in[13];
    const float* A3 = (const float*)d_in[14];
    const float* B3 = (const float*)d_in[15];
    const float* R3 = (const float*)d_in[16];

    float* ws = (float*)d_ws;
    float* C1 = ws;                      // 4096*512          = 2,097,152 f
    float* C2 = ws + 2097152;            // 2 * 4096*128      = 1,048,576 f
    float* C3 = ws + 3145728;            // 4096*1024         = 4,194,304 f
    unsigned short* us = (unsigned short*)(ws + 7340032);
    unsigned short* xh   = us;                 // 2,097,152
    unsigned short* xl   = xh  + 2097152;
    unsigned short* h1h  = xl  + 2097152;      // 2,097,152
    unsigned short* h1l  = h1h + 2097152;
    unsigned short* W1h  = h1l + 2097152;      // 262,144
    unsigned short* W1l  = W1h + 262144;
    unsigned short* Wc2h = W1l + 262144;       // 65,536 (128x512)
    unsigned short* Wc2l = Wc2h + 65536;
    unsigned short* Wc3h = Wc2l + 65536;       // 65,536 (1024x64)
    unsigned short* Wc3l = Wc3h + 65536;
    unsigned short* h2h  = Wc3l + 65536;       // 262,144 (4096x64)
    unsigned short* h2l  = h2h + 262144;

    dim3 blk(256);

    // 0) fp32 -> bf16 hi/lo planes (x, W1, [M2;R2], [W3;R3])
    convk<<<2432, blk, 0, stream>>>(x, W1, M2, R2, W3, R3,
                                    xh, xl, W1h, W1l, Wc2h, Wc2l, Wc3h, Wc3l);

    // 1) C1 = x @ W1^T   (4096x512, K=512)
    gemm_bf3<<<dim3(8, 32, 1), blk, 0, stream>>>(xh, xl, W1h, W1l, C1, ROWS, 512, 512, 512);
    //    h1 = RN(C1) + x  -> bf16 planes
    ln_rn_kernel<<<ROWS, blk, 0, stream>>>(C1, 512, x, 512, g1, b1, B1, A1,
                                           nullptr, h1h, h1l);

    // 2) C2 = h1 @ [M2;R2]^T  (4096x128, K=512, split-K=2)
    gemm_bf3<<<dim3(2, 32, 2), blk, 0, stream>>>(h1h, h1l, Wc2h, Wc2l, C2, ROWS, 128, 512, 256);
    //    h2 = TS(C2) -> bf16 planes
    ts_kernel<<<SEQ, blk, 0, stream>>>(C2, g2, b2, P2, h2h, h2l);

    // 3) C3 = h2 @ [W3;R3]^T  (4096x1024, K=64)
    gemm_bf3<<<dim3(16, 32, 1), blk, 0, stream>>>(h2h, h2l, Wc3h, Wc3l, C3, ROWS, 1024, 64, 64);
    //    out = RN(C3[:, :512]) + C3[:, 512:]
    ln_rn_kernel<<<ROWS, blk, 0, stream>>>(C3, 1024, C3 + 512, 1024, g3, b3, B3, A3,
                                           (float*)d_out, nullptr, nullptr);
}